// Round 2
// baseline (97.873 us; speedup 1.0000x reference)
//
#include <hip/hip_runtime.h>

// ConjunctionLayer: out[b,j] = -1 / (-1 + sum_i log(1 - (1-x[b,i]) * W[j,i]))
// B=4096, INPUT_DIM=512, N=128, fp32.
//
// R2: W is wave-uniform -> read it through the SCALAR path (s_load), not LDS.
// R1 was LDS-pipe-bound: 512 broadcast ds_read_b128 per wave ~= 49k cyc/CU
// (~20 us) vs a ~5 us VALU floor. readfirstlane on the row index coerces the
// address to uniform so the compiler selects SMEM; W then feeds v_pk_fma_f32
// as the one legal SGPR operand (x=VGPR, W=SGPR, 1.0=inline const).
//
// Mapping: lane <-> b (64 b per wave). Block = 4 waves = 64 b x 16 j, each
// wave owns 4 j across K=512; accumulators in VGPRs, no reduction.
// Product-of-16 z's -> one v_log_f32 per 16 elements (z in (0.5,1], so the
// partial product >= 0.5^16 stays normal fp32).

typedef float v2f __attribute__((ext_vector_type(2)));

constexpr int IDIM    = 512;
constexpr int NOUT    = 128;
constexpr int BTOT    = 4096;
constexpr int JT      = 16;            // j per block
constexpr int JW      = 4;             // j per wave
constexpr int BGROUPS = BTOT / 64;     // 64
constexpr int JGROUPS = NOUT / JT;     // 8
constexpr float LN2   = 0.69314718055994530942f;

__device__ __forceinline__ v2f mk2(float a, float b) {
    v2f r; r.x = a; r.y = b; return r;
}

__global__ __launch_bounds__(256, 2)
void conj_kernel(const float* __restrict__ x,
                 const float* __restrict__ W,
                 float* __restrict__ out)
{
    __shared__ float s_acc[64][JT + 1];     // output transpose tile, 4.25 KB

    const int tid = threadIdx.x;
    // bg = blockIdx % 64: the 8 j-sibling blocks sharing an x slice land on
    // the same XCD under idx%8 round-robin -> x served from that L2.
    const int bg = blockIdx.x & (BGROUPS - 1);
    const int jg = blockIdx.x >> 6;
    const int j0 = jg * JT;
    const int b0 = bg * 64;

    const int wave = tid >> 6;
    const int lane = tid & 63;
    const int b    = b0 + lane;
    const int jl0  = wave * JW;

    // Wave-uniform W row bases (readfirstlane -> SGPR -> SMEM selection).
    const float* wrow0 = W + (size_t)__builtin_amdgcn_readfirstlane(j0 + jl0 + 0) * IDIM;
    const float* wrow1 = W + (size_t)__builtin_amdgcn_readfirstlane(j0 + jl0 + 1) * IDIM;
    const float* wrow2 = W + (size_t)__builtin_amdgcn_readfirstlane(j0 + jl0 + 2) * IDIM;
    const float* wrow3 = W + (size_t)__builtin_amdgcn_readfirstlane(j0 + jl0 + 3) * IDIM;

    float acc[JW];
    #pragma unroll
    for (int jj = 0; jj < JW; ++jj) acc[jj] = 0.0f;

    const float4* xrow = (const float4*)(x + (size_t)b * IDIM);

    // Software-pipeline the per-lane 64 B x chunk one t ahead.
    float4 xa0 = xrow[0], xa1 = xrow[1], xa2 = xrow[2], xa3 = xrow[3];

    for (int t = 0; t < IDIM / 16; ++t) {
        const int tn = (t + 1) & 31;          // last prefetch re-reads t=0 (in-bounds)
        float4 xb0 = xrow[tn * 4 + 0];
        float4 xb1 = xrow[tn * 4 + 1];
        float4 xb2 = xrow[tn * 4 + 2];
        float4 xb3 = xrow[tn * 4 + 3];

        v2f xm[8];
        xm[0] = mk2(xa0.x, xa0.y) - 1.0f;
        xm[1] = mk2(xa0.z, xa0.w) - 1.0f;
        xm[2] = mk2(xa1.x, xa1.y) - 1.0f;
        xm[3] = mk2(xa1.z, xa1.w) - 1.0f;
        xm[4] = mk2(xa2.x, xa2.y) - 1.0f;
        xm[5] = mk2(xa2.z, xa2.w) - 1.0f;
        xm[6] = mk2(xa3.x, xa3.y) - 1.0f;
        xm[7] = mk2(xa3.z, xa3.w) - 1.0f;

        const float* wr[JW] = { wrow0, wrow1, wrow2, wrow3 };
        #pragma unroll
        for (int jj = 0; jj < JW; ++jj) {
            // Uniform address -> s_load_dwordx4/x16; values live in SGPRs.
            const float4* wp = (const float4*)(wr[jj] + t * 16);
            float4 w0 = wp[0], w1 = wp[1], w2 = wp[2], w3 = wp[3];

            // z = 1 + (x-1)*w  (fp-contract -> v_pk_fma_f32, SGPR W operand)
            v2f z0 = xm[0] * mk2(w0.x, w0.y) + 1.0f;
            v2f z1 = xm[1] * mk2(w0.z, w0.w) + 1.0f;
            v2f z2 = xm[2] * mk2(w1.x, w1.y) + 1.0f;
            v2f z3 = xm[3] * mk2(w1.z, w1.w) + 1.0f;
            v2f z4 = xm[4] * mk2(w2.x, w2.y) + 1.0f;
            v2f z5 = xm[5] * mk2(w2.z, w2.w) + 1.0f;
            v2f z6 = xm[6] * mk2(w3.x, w3.y) + 1.0f;
            v2f z7 = xm[7] * mk2(w3.z, w3.w) + 1.0f;

            // product tree of 16 z's -> one log
            v2f p0 = z0 * z1, p1 = z2 * z3, p2 = z4 * z5, p3 = z6 * z7;
            v2f q0 = p0 * p1, q1 = p2 * p3;
            v2f q  = q0 * q1;
            float p = q.x * q.y;                 // p in (0.5^16, 1]
            acc[jj] += __builtin_amdgcn_logf(p); // v_log_f32 (log2)
        }

        xa0 = xb0; xa1 = xb1; xa2 = xb2; xa3 = xb3;
    }

    // Transpose through LDS for coalesced float4 stores.
    #pragma unroll
    for (int jj = 0; jj < JW; ++jj)
        s_acc[lane][jl0 + jj] = acc[jj];   // stride 17: conflict-free
    __syncthreads();

    const int r = tid >> 2;        // b-row within tile
    const int c = tid & 3;         // float4 within 16-j row
    const float* sv = &s_acc[r][c * 4];
    float4 v;
    v.x = 1.0f / (1.0f - LN2 * sv[0]);
    v.y = 1.0f / (1.0f - LN2 * sv[1]);
    v.z = 1.0f / (1.0f - LN2 * sv[2]);
    v.w = 1.0f / (1.0f - LN2 * sv[3]);
    *(float4*)(out + (size_t)(b0 + r) * NOUT + j0 + c * 4) = v;
}

extern "C" void kernel_launch(void* const* d_in, const int* in_sizes, int n_in,
                              void* d_out, int out_size, void* d_ws, size_t ws_size,
                              hipStream_t stream) {
    const float* x = (const float*)d_in[0];   // (4096, 512) fp32
    const float* W = (const float*)d_in[1];   // (128, 512) fp32
    float* out = (float*)d_out;               // (4096, 128) fp32

    dim3 grid(BGROUPS * JGROUPS);             // 512 blocks
    dim3 block(256);
    hipLaunchKernelGGL(conj_kernel, grid, block, 0, stream, x, W, out);
}

// Round 4
// 75.899 us; speedup vs baseline: 1.2895x; 1.2895x over previous
//
#include <hip/hip_runtime.h>

// ConjunctionLayer: out[b,j] = -1 / (-1 + sum_i log(1 - (1-x[b,i]) * W[j,i]))
// B=4096, INPUT_DIM=512, N=128, fp32.
//
// R3b: invert the mapping so the hot loop is VMEM-light and VALU-dense.
//   lane <-> j (64 j per wave; j-half h covers N=128), wave <-> K-chunk
//   (8 waves x 64 i = 512). W[j, k0:k0+64] is loop-invariant per lane ->
//   held in VGPRs (w + u = 1-w, 128 VGPRs); z = fma(x, w, u).
//   x[b,i] is wave-uniform -> uniform loads (4 x dwordx4 per b), off the
//   VALU critical path. Product-of-16 z's -> one v_log_f32 per 16 i
//   (z in (0.5,1], partial product >= 0.5^16 stays normal fp32).
//   Cross-wave K-reduction (sum of logs) through a 32 KB LDS tile per block.
//
// R2 failure mode this fixes: VGPR_Count=24 showed the compiler sank all x
// prefetch -> serial VMEM latency chain at 2 waves/SIMD (VALUBusy 17%).
// R3 compile fix: no __builtin_shufflevector with loop-carried index; x is
// read as v2f[8] with constant subscripts (backend merges into dwordx4).

typedef float v2f __attribute__((ext_vector_type(2)));
typedef float v4f __attribute__((ext_vector_type(4)));

constexpr int IDIM  = 512;
constexpr int NOUT  = 128;
constexpr int BTOT  = 4096;
constexpr int KC    = 64;            // i per wave
constexpr int NB    = 16;            // b per block
constexpr int GB    = BTOT / NB;     // 256 b-groups
constexpr float LN2 = 0.69314718055994530942f;

// product-of-16 -> one log2. xp points at x[b, i0] (wave-uniform, 16B-aligned),
// w/u = per-lane W fragments for the same 16 i.
__device__ __forceinline__ float grouplog(const v2f* __restrict__ xp,
                                          const v2f* w, const v2f* u) {
    v2f z[8];
    #pragma unroll
    for (int p = 0; p < 8; ++p)
        z[p] = xp[p] * w[p] + u[p];       // v_pk_fma_f32: z = x*w + (1-w)
    v2f a = (z[0] * z[1]) * (z[2] * z[3]);
    v2f c = (z[4] * z[5]) * (z[6] * z[7]);
    v2f q = a * c;
    return __builtin_amdgcn_logf(q.x * q.y);   // v_log_f32 (log2)
}

__global__ __launch_bounds__(512, 2)
void conj_kernel(const float* __restrict__ x,
                 const float* __restrict__ W,
                 float* __restrict__ out)
{
    __shared__ float s_p[NB * 8 * 64];   // [bi][wave][lane] partial log-sums, 32 KB

    const int tid  = threadIdx.x;
    const int lane = tid & 63;
    const int wv   = __builtin_amdgcn_readfirstlane(tid >> 6);   // 0..7, SGPR
    const int h    = blockIdx.x >> 8;        // j-half; h-pairs 256 apart -> same XCD
    const int bg   = blockIdx.x & (GB - 1);
    const int b0   = bg * NB;
    const int j    = h * 64 + lane;
    const int k0   = wv * KC;

    // Loop-invariant W fragment: w = W[j, k0:k0+64], u = 1 - w. 128 VGPRs.
    v2f w[32], u[32];
    {
        const v4f* wp = (const v4f*)(W + (size_t)j * IDIM + k0);
        #pragma unroll
        for (int qd = 0; qd < 16; ++qd) {
            v4f t = wp[qd];
            v2f lo; lo.x = t.x; lo.y = t.y;
            v2f hi; hi.x = t.z; hi.y = t.w;
            w[2 * qd]     = lo;
            w[2 * qd + 1] = hi;
            u[2 * qd]     = 1.0f - lo;
            u[2 * qd + 1] = 1.0f - hi;
        }
    }

    const float* xbase = x + (size_t)b0 * IDIM + k0;   // wave-uniform

    for (int bi = 0; bi < NB; ++bi) {
        const v2f* xp = (const v2f*)(xbase + (size_t)bi * IDIM);
        float s = grouplog(xp + 0,  &w[0],  &u[0])
                + grouplog(xp + 8,  &w[8],  &u[8])
                + grouplog(xp + 16, &w[16], &u[16])
                + grouplog(xp + 24, &w[24], &u[24]);
        s_p[bi * 512 + wv * 64 + lane] = s;    // lanes consecutive: no conflict
    }
    __syncthreads();

    // Reduce the 8 K-chunks, finalize, coalesced store.
    #pragma unroll
    for (int r = 0; r < (NB * 64) / 512; ++r) {   // 2 outputs/thread
        const int idx = tid + r * 512;
        const int bi  = idx >> 6;
        const int l   = idx & 63;
        float sum = 0.0f;
        #pragma unroll
        for (int wq = 0; wq < 8; ++wq)
            sum += s_p[bi * 512 + wq * 64 + l];   // lanes consecutive: no conflict
        out[(size_t)(b0 + bi) * NOUT + h * 64 + l] = 1.0f / (1.0f - LN2 * sum);
    }
}

extern "C" void kernel_launch(void* const* d_in, const int* in_sizes, int n_in,
                              void* d_out, int out_size, void* d_ws, size_t ws_size,
                              hipStream_t stream) {
    const float* x = (const float*)d_in[0];   // (4096, 512) fp32
    const float* W = (const float*)d_in[1];   // (128, 512) fp32
    float* out = (float*)d_out;               // (4096, 128) fp32

    dim3 grid(2 * GB);                        // 512 blocks (j-half major)
    dim3 block(512);                          // 8 waves
    hipLaunchKernelGGL(conj_kernel, grid, block, 0, stream, x, W, out);
}